// Round 1
// baseline (139.790 us; speedup 1.0000x reference)
//
#include <hip/hip_runtime.h>

// Problem geometry: B=64, A=9, H=W=128, C=1000
static constexpr int HW4      = 128 * 128 / 4;   // 4096 float4 per (b,a,channel) plane
static constexpr int BA       = 64 * 9;          // 576
static constexpr int N4       = BA * HW4;        // 2,359,296 float4 units
static constexpr float LOGCLAMP = -100.0f;

// ws layout: ws[0]=no_obj_confi, ws[1]=obj_confi, ws[2]=obj_coor, ws[3]=img_class

__global__ __launch_bounds__(256) void main_loss_kernel(
    const float4* __restrict__ objects,   // (BA, HW4)
    const float4* __restrict__ locs,      // (BA, 4, HW4)
    const float4* __restrict__ gt,        // (BA, 5, HW4)
    float* __restrict__ ws)
{
    float s_noobj = 0.0f, s_obj = 0.0f, s_coor = 0.0f;

    const int stride = gridDim.x * blockDim.x;
    for (int u = blockIdx.x * blockDim.x + threadIdx.x; u < N4; u += stride) {
        const int ba = u >> 12;          // / 4096
        const int r  = u & 4095;         // % 4096
        const int gbase = ba * 5 * HW4;
        const int lbase = ba * 4 * HW4;

        const float4 o = objects[u];
        const float4 m = gt[gbase + r];

        // sum over 4 coords of (loc - gt)^2, per lane-component
        float sqx = 0.f, sqy = 0.f, sqz = 0.f, sqw = 0.f;
        #pragma unroll
        for (int c = 0; c < 4; ++c) {
            const float4 l = locs[lbase + c * HW4 + r];
            const float4 g = gt[gbase + (c + 1) * HW4 + r];
            const float dx = l.x - g.x, dy = l.y - g.y,
                        dz = l.z - g.z, dw = l.w - g.w;
            sqx += dx * dx; sqy += dy * dy; sqz += dz * dz; sqw += dw * dw;
        }

        // per-component confidence + coord terms
        {
            float lp  = fmaxf(__logf(o.x),        LOGCLAMP);
            float l1  = fmaxf(__logf(1.0f - o.x), LOGCLAMP);
            s_noobj += (1.0f - m.x) * (-l1);
            s_obj   += m.x * (-lp);
            s_coor  += m.x * sqx;
        }
        {
            float lp  = fmaxf(__logf(o.y),        LOGCLAMP);
            float l1  = fmaxf(__logf(1.0f - o.y), LOGCLAMP);
            s_noobj += (1.0f - m.y) * (-l1);
            s_obj   += m.y * (-lp);
            s_coor  += m.y * sqy;
        }
        {
            float lp  = fmaxf(__logf(o.z),        LOGCLAMP);
            float l1  = fmaxf(__logf(1.0f - o.z), LOGCLAMP);
            s_noobj += (1.0f - m.z) * (-l1);
            s_obj   += m.z * (-lp);
            s_coor  += m.z * sqz;
        }
        {
            float lp  = fmaxf(__logf(o.w),        LOGCLAMP);
            float l1  = fmaxf(__logf(1.0f - o.w), LOGCLAMP);
            s_noobj += (1.0f - m.w) * (-l1);
            s_obj   += m.w * (-lp);
            s_coor  += m.w * sqw;
        }
    }

    // wave64 reduce all three sums
    #pragma unroll
    for (int off = 32; off > 0; off >>= 1) {
        s_noobj += __shfl_down(s_noobj, off, 64);
        s_obj   += __shfl_down(s_obj,   off, 64);
        s_coor  += __shfl_down(s_coor,  off, 64);
    }

    __shared__ float red[3][4];
    const int lane = threadIdx.x & 63;
    const int wid  = threadIdx.x >> 6;
    if (lane == 0) {
        red[0][wid] = s_noobj;
        red[1][wid] = s_obj;
        red[2][wid] = s_coor;
    }
    __syncthreads();
    if (threadIdx.x == 0) {
        atomicAdd(&ws[0], red[0][0] + red[0][1] + red[0][2] + red[0][3]);
        atomicAdd(&ws[1], red[1][0] + red[1][1] + red[1][2] + red[1][3]);
        atomicAdd(&ws[2], red[2][0] + red[2][1] + red[2][2] + red[2][3]);
    }
}

// img_class_loss: one block per batch row, C=1000
__global__ __launch_bounds__(256) void class_loss_kernel(
    const float* __restrict__ scores,   // (64, 1000)
    const int*   __restrict__ label,    // (64,)
    float* __restrict__ ws)
{
    const int b = blockIdx.x;
    const float* row = scores + b * 1000;

    float mx = -INFINITY;
    for (int i = threadIdx.x; i < 1000; i += 256) mx = fmaxf(mx, row[i]);
    #pragma unroll
    for (int off = 32; off > 0; off >>= 1) mx = fmaxf(mx, __shfl_down(mx, off, 64));

    __shared__ float smax[4];
    const int lane = threadIdx.x & 63;
    const int wid  = threadIdx.x >> 6;
    if (lane == 0) smax[wid] = mx;
    __syncthreads();
    mx = fmaxf(fmaxf(smax[0], smax[1]), fmaxf(smax[2], smax[3]));

    float se = 0.0f;
    for (int i = threadIdx.x; i < 1000; i += 256) se += __expf(row[i] - mx);
    #pragma unroll
    for (int off = 32; off > 0; off >>= 1) se += __shfl_down(se, off, 64);

    __shared__ float ssum[4];
    if (lane == 0) ssum[wid] = se;
    __syncthreads();
    if (threadIdx.x == 0) {
        se = ssum[0] + ssum[1] + ssum[2] + ssum[3];
        const float logp = row[label[b]] - mx - __logf(se);
        atomicAdd(&ws[3], -logp * (1.0f / 64.0f));   // mean over B
    }
}

__global__ void finalize_kernel(const float* __restrict__ ws, float* __restrict__ out)
{
    // IMG_CLASS_WEIGHT*class + (0.5*noobj + 1.0*obj + 5.0*coor)/B
    out[0] = ws[3] + (0.5f * ws[0] + 1.0f * ws[1] + 5.0f * ws[2]) * (1.0f / 64.0f);
}

extern "C" void kernel_launch(void* const* d_in, const int* in_sizes, int n_in,
                              void* d_out, int out_size, void* d_ws, size_t ws_size,
                              hipStream_t stream)
{
    const float* objects = (const float*)d_in[0];   // (64,9,128,128)
    const float* scores  = (const float*)d_in[1];   // (64,1000)
    const float* locs    = (const float*)d_in[2];   // (64,9,4,128,128)
    const int*   label   = (const int*)d_in[3];     // (64,)
    const float* gt      = (const float*)d_in[4];   // (64,9,5,128,128)
    float* ws  = (float*)d_ws;
    float* out = (float*)d_out;

    hipMemsetAsync(ws, 0, 4 * sizeof(float), stream);

    main_loss_kernel<<<2048, 256, 0, stream>>>(
        (const float4*)objects, (const float4*)locs, (const float4*)gt, ws);
    class_loss_kernel<<<64, 256, 0, stream>>>(scores, label, ws);
    finalize_kernel<<<1, 1, 0, stream>>>(ws, out);
}

// Round 2
// 126.007 us; speedup vs baseline: 1.1094x; 1.1094x over previous
//
#include <hip/hip_runtime.h>

// Problem geometry: B=64, A=9, H=W=128, C=1000
// N4 = 64*9*4096 = 2,359,296 float4 units over the (B,A,H,W) space.
// Grid: 2304 blocks x 256 threads x 4 units/thread = exact cover.
// Block b owns units [b*1024, b*1024+1024): never crosses a 4096-unit
// channel plane, so ba = b>>2 and the in-plane base = (b&3)*1024 are scalar.
static constexpr int HW4 = 4096;
static constexpr float LOGCLAMP = -100.0f;

// ws layout: ws[0]=no_obj_confi, ws[1]=obj_confi, ws[2]=obj_coor, ws[3]=img_class

__device__ __forceinline__ void accum_one(
    const float4 o, const float4 m,
    const float4 l0, const float4 l1, const float4 l2, const float4 l3,
    const float4 g0, const float4 g1, const float4 g2, const float4 g3,
    float& s_noobj, float& s_obj, float& s_coor)
{
    float dx, dy, dz, dw;
    float sqx, sqy, sqz, sqw;
    dx = l0.x - g0.x; dy = l0.y - g0.y; dz = l0.z - g0.z; dw = l0.w - g0.w;
    sqx = dx * dx; sqy = dy * dy; sqz = dz * dz; sqw = dw * dw;
    dx = l1.x - g1.x; dy = l1.y - g1.y; dz = l1.z - g1.z; dw = l1.w - g1.w;
    sqx += dx * dx; sqy += dy * dy; sqz += dz * dz; sqw += dw * dw;
    dx = l2.x - g2.x; dy = l2.y - g2.y; dz = l2.z - g2.z; dw = l2.w - g2.w;
    sqx += dx * dx; sqy += dy * dy; sqz += dz * dz; sqw += dw * dw;
    dx = l3.x - g3.x; dy = l3.y - g3.y; dz = l3.z - g3.z; dw = l3.w - g3.w;
    sqx += dx * dx; sqy += dy * dy; sqz += dz * dz; sqw += dw * dw;

    {
        const float lp = fmaxf(__logf(o.x),        LOGCLAMP);
        const float l1m = fmaxf(__logf(1.0f - o.x), LOGCLAMP);
        s_noobj += (1.0f - m.x) * (-l1m);
        s_obj   += m.x * (-lp);
        s_coor  += m.x * sqx;
    }
    {
        const float lp = fmaxf(__logf(o.y),        LOGCLAMP);
        const float l1m = fmaxf(__logf(1.0f - o.y), LOGCLAMP);
        s_noobj += (1.0f - m.y) * (-l1m);
        s_obj   += m.y * (-lp);
        s_coor  += m.y * sqy;
    }
    {
        const float lp = fmaxf(__logf(o.z),        LOGCLAMP);
        const float l1m = fmaxf(__logf(1.0f - o.z), LOGCLAMP);
        s_noobj += (1.0f - m.z) * (-l1m);
        s_obj   += m.z * (-lp);
        s_coor  += m.z * sqz;
    }
    {
        const float lp = fmaxf(__logf(o.w),        LOGCLAMP);
        const float l1m = fmaxf(__logf(1.0f - o.w), LOGCLAMP);
        s_noobj += (1.0f - m.w) * (-l1m);
        s_obj   += m.w * (-lp);
        s_coor  += m.w * sqw;
    }
}

__global__ __launch_bounds__(256) void main_loss_kernel(
    const float4* __restrict__ objects,   // (BA, HW4)
    const float4* __restrict__ locs,      // (BA, 4, HW4)
    const float4* __restrict__ gt,        // (BA, 5, HW4)
    float* __restrict__ ws)
{
    const int b   = blockIdx.x;
    const int tid = threadIdx.x;

    // Scalar (wave-uniform) bases.
    const float4* __restrict__ pO = objects + b * 1024;
    const float4* __restrict__ pG = gt   + (b >> 2) * 5 * HW4 + (b & 3) * 1024;
    const float4* __restrict__ pL = locs + (b >> 2) * 4 * HW4 + (b & 3) * 1024;

    float s_noobj = 0.0f, s_obj = 0.0f, s_coor = 0.0f;

    // 4 units/thread, batched 2 deep: 20 float4 loads in flight per batch.
    #pragma unroll
    for (int kk = 0; kk < 4; kk += 2) {
        const int r0 = kk * 256 + tid;
        const int r1 = r0 + 256;

        // ---- issue all 20 loads ----
        const float4 oA = pO[r0];
        const float4 oB = pO[r1];
        const float4 mA = pG[r0];
        const float4 mB = pG[r1];
        const float4 lA0 = pL[0 * HW4 + r0], lA1 = pL[1 * HW4 + r0],
                     lA2 = pL[2 * HW4 + r0], lA3 = pL[3 * HW4 + r0];
        const float4 gA0 = pG[1 * HW4 + r0], gA1 = pG[2 * HW4 + r0],
                     gA2 = pG[3 * HW4 + r0], gA3 = pG[4 * HW4 + r0];
        const float4 lB0 = pL[0 * HW4 + r1], lB1 = pL[1 * HW4 + r1],
                     lB2 = pL[2 * HW4 + r1], lB3 = pL[3 * HW4 + r1];
        const float4 gB0 = pG[1 * HW4 + r1], gB1 = pG[2 * HW4 + r1],
                     gB2 = pG[3 * HW4 + r1], gB3 = pG[4 * HW4 + r1];

        // ---- then compute ----
        accum_one(oA, mA, lA0, lA1, lA2, lA3, gA0, gA1, gA2, gA3,
                  s_noobj, s_obj, s_coor);
        accum_one(oB, mB, lB0, lB1, lB2, lB3, gB0, gB1, gB2, gB3,
                  s_noobj, s_obj, s_coor);
    }

    // wave64 reduce all three sums
    #pragma unroll
    for (int off = 32; off > 0; off >>= 1) {
        s_noobj += __shfl_down(s_noobj, off, 64);
        s_obj   += __shfl_down(s_obj,   off, 64);
        s_coor  += __shfl_down(s_coor,  off, 64);
    }

    __shared__ float red[3][4];
    const int lane = threadIdx.x & 63;
    const int wid  = threadIdx.x >> 6;
    if (lane == 0) {
        red[0][wid] = s_noobj;
        red[1][wid] = s_obj;
        red[2][wid] = s_coor;
    }
    __syncthreads();
    if (threadIdx.x == 0) {
        atomicAdd(&ws[0], red[0][0] + red[0][1] + red[0][2] + red[0][3]);
        atomicAdd(&ws[1], red[1][0] + red[1][1] + red[1][2] + red[1][3]);
        atomicAdd(&ws[2], red[2][0] + red[2][1] + red[2][2] + red[2][3]);
    }
}

// img_class_loss: one block per batch row, C=1000
__global__ __launch_bounds__(256) void class_loss_kernel(
    const float* __restrict__ scores,   // (64, 1000)
    const int*   __restrict__ label,    // (64,)
    float* __restrict__ ws)
{
    const int b = blockIdx.x;
    const float* row = scores + b * 1000;

    float mx = -INFINITY;
    for (int i = threadIdx.x; i < 1000; i += 256) mx = fmaxf(mx, row[i]);
    #pragma unroll
    for (int off = 32; off > 0; off >>= 1) mx = fmaxf(mx, __shfl_down(mx, off, 64));

    __shared__ float smax[4];
    const int lane = threadIdx.x & 63;
    const int wid  = threadIdx.x >> 6;
    if (lane == 0) smax[wid] = mx;
    __syncthreads();
    mx = fmaxf(fmaxf(smax[0], smax[1]), fmaxf(smax[2], smax[3]));

    float se = 0.0f;
    for (int i = threadIdx.x; i < 1000; i += 256) se += __expf(row[i] - mx);
    #pragma unroll
    for (int off = 32; off > 0; off >>= 1) se += __shfl_down(se, off, 64);

    __shared__ float ssum[4];
    if (lane == 0) ssum[wid] = se;
    __syncthreads();
    if (threadIdx.x == 0) {
        se = ssum[0] + ssum[1] + ssum[2] + ssum[3];
        const float logp = row[label[b]] - mx - __logf(se);
        atomicAdd(&ws[3], -logp * (1.0f / 64.0f));   // mean over B
    }
}

__global__ void finalize_kernel(const float* __restrict__ ws, float* __restrict__ out)
{
    // IMG_CLASS_WEIGHT*class + (0.5*noobj + 1.0*obj + 5.0*coor)/B
    out[0] = ws[3] + (0.5f * ws[0] + 1.0f * ws[1] + 5.0f * ws[2]) * (1.0f / 64.0f);
}

extern "C" void kernel_launch(void* const* d_in, const int* in_sizes, int n_in,
                              void* d_out, int out_size, void* d_ws, size_t ws_size,
                              hipStream_t stream)
{
    const float* objects = (const float*)d_in[0];   // (64,9,128,128)
    const float* scores  = (const float*)d_in[1];   // (64,1000)
    const float* locs    = (const float*)d_in[2];   // (64,9,4,128,128)
    const int*   label   = (const int*)d_in[3];     // (64,)
    const float* gt      = (const float*)d_in[4];   // (64,9,5,128,128)
    float* ws  = (float*)d_ws;
    float* out = (float*)d_out;

    hipMemsetAsync(ws, 0, 4 * sizeof(float), stream);

    main_loss_kernel<<<2304, 256, 0, stream>>>(
        (const float4*)objects, (const float4*)locs, (const float4*)gt, ws);
    class_loss_kernel<<<64, 256, 0, stream>>>(scores, label, ws);
    finalize_kernel<<<1, 1, 0, stream>>>(ws, out);
}

// Round 3
// 123.732 us; speedup vs baseline: 1.1298x; 1.0184x over previous
//
#include <hip/hip_runtime.h>

// Problem geometry: B=64, A=9, H=W=128, C=1000
// N4 = 64*9*4096 = 2,359,296 float4 units over the (B,A,H,W) space.
// Grid: 2304 blocks x 256 threads x 4 units/thread = exact cover.
// Block b owns units [b*1024, b*1024+1024): never crosses a 4096-unit
// channel plane, so ba = b>>2 and in-plane base = (b&3)*1024 are scalar.
static constexpr int HW4 = 4096;
static constexpr float LOGCLAMP = -100.0f;

// ws layout: ws[0]=no_obj_confi, ws[1]=obj_confi, ws[2]=obj_coor, ws[3]=img_class

struct U10 {
    float4 o, m, l0, l1, l2, l3, g0, g1, g2, g3;
};

__device__ __forceinline__ void load_unit(
    const float4* __restrict__ pO, const float4* __restrict__ pL,
    const float4* __restrict__ pG, int r, U10& u)
{
    u.o  = pO[r];
    u.m  = pG[r];
    u.l0 = pL[0 * HW4 + r];
    u.l1 = pL[1 * HW4 + r];
    u.l2 = pL[2 * HW4 + r];
    u.l3 = pL[3 * HW4 + r];
    u.g0 = pG[1 * HW4 + r];
    u.g1 = pG[2 * HW4 + r];
    u.g2 = pG[3 * HW4 + r];
    u.g3 = pG[4 * HW4 + r];
}

__device__ __forceinline__ void accum_unit(
    const U10& u, float& s_noobj, float& s_obj, float& s_coor)
{
    float dx, dy, dz, dw;
    float sqx, sqy, sqz, sqw;
    dx = u.l0.x - u.g0.x; dy = u.l0.y - u.g0.y; dz = u.l0.z - u.g0.z; dw = u.l0.w - u.g0.w;
    sqx = dx * dx; sqy = dy * dy; sqz = dz * dz; sqw = dw * dw;
    dx = u.l1.x - u.g1.x; dy = u.l1.y - u.g1.y; dz = u.l1.z - u.g1.z; dw = u.l1.w - u.g1.w;
    sqx += dx * dx; sqy += dy * dy; sqz += dz * dz; sqw += dw * dw;
    dx = u.l2.x - u.g2.x; dy = u.l2.y - u.g2.y; dz = u.l2.z - u.g2.z; dw = u.l2.w - u.g2.w;
    sqx += dx * dx; sqy += dy * dy; sqz += dz * dz; sqw += dw * dw;
    dx = u.l3.x - u.g3.x; dy = u.l3.y - u.g3.y; dz = u.l3.z - u.g3.z; dw = u.l3.w - u.g3.w;
    sqx += dx * dx; sqy += dy * dy; sqz += dz * dz; sqw += dw * dw;

    {
        const float lp  = fmaxf(__logf(u.o.x),        LOGCLAMP);
        const float l1m = fmaxf(__logf(1.0f - u.o.x), LOGCLAMP);
        s_noobj += (1.0f - u.m.x) * (-l1m);
        s_obj   += u.m.x * (-lp);
        s_coor  += u.m.x * sqx;
    }
    {
        const float lp  = fmaxf(__logf(u.o.y),        LOGCLAMP);
        const float l1m = fmaxf(__logf(1.0f - u.o.y), LOGCLAMP);
        s_noobj += (1.0f - u.m.y) * (-l1m);
        s_obj   += u.m.y * (-lp);
        s_coor  += u.m.y * sqy;
    }
    {
        const float lp  = fmaxf(__logf(u.o.z),        LOGCLAMP);
        const float l1m = fmaxf(__logf(1.0f - u.o.z), LOGCLAMP);
        s_noobj += (1.0f - u.m.z) * (-l1m);
        s_obj   += u.m.z * (-lp);
        s_coor  += u.m.z * sqz;
    }
    {
        const float lp  = fmaxf(__logf(u.o.w),        LOGCLAMP);
        const float l1m = fmaxf(__logf(1.0f - u.o.w), LOGCLAMP);
        s_noobj += (1.0f - u.m.w) * (-l1m);
        s_obj   += u.m.w * (-lp);
        s_coor  += u.m.w * sqw;
    }
}

__global__ __launch_bounds__(256, 2) void main_loss_kernel(
    const float4* __restrict__ objects,   // (BA, HW4)
    const float4* __restrict__ locs,      // (BA, 4, HW4)
    const float4* __restrict__ gt,        // (BA, 5, HW4)
    float* __restrict__ ws)
{
    const int b   = blockIdx.x;
    const int tid = threadIdx.x;

    // Scalar (wave-uniform) bases.
    const float4* __restrict__ pO = objects + b * 1024;
    const float4* __restrict__ pG = gt   + (b >> 2) * 5 * HW4 + (b & 3) * 1024;
    const float4* __restrict__ pL = locs + (b >> 2) * 4 * HW4 + (b & 3) * 1024;

    float s_noobj = 0.0f, s_obj = 0.0f, s_coor = 0.0f;

    // 2-deep software pipeline over 4 units/thread. sched_barrier(0)
    // fences keep each 10-load batch issued as a group ABOVE the compute
    // of the previous batch: accum(k) waits on vmcnt(10) while batch k+1
    // stays in flight. ~80 VGPRs of load data live by construction.
    U10 bufA, bufB;

    load_unit(pO, pL, pG, tid + 0 * 256, bufA);   // batch 0
    load_unit(pO, pL, pG, tid + 1 * 256, bufB);   // batch 1
    __builtin_amdgcn_sched_barrier(0);

    accum_unit(bufA, s_noobj, s_obj, s_coor);     // waits batch 0 only
    load_unit(pO, pL, pG, tid + 2 * 256, bufA);   // batch 2
    __builtin_amdgcn_sched_barrier(0);

    accum_unit(bufB, s_noobj, s_obj, s_coor);     // waits batch 1 only
    load_unit(pO, pL, pG, tid + 3 * 256, bufB);   // batch 3
    __builtin_amdgcn_sched_barrier(0);

    accum_unit(bufA, s_noobj, s_obj, s_coor);
    accum_unit(bufB, s_noobj, s_obj, s_coor);

    // wave64 reduce all three sums
    #pragma unroll
    for (int off = 32; off > 0; off >>= 1) {
        s_noobj += __shfl_down(s_noobj, off, 64);
        s_obj   += __shfl_down(s_obj,   off, 64);
        s_coor  += __shfl_down(s_coor,  off, 64);
    }

    __shared__ float red[3][4];
    const int lane = threadIdx.x & 63;
    const int wid  = threadIdx.x >> 6;
    if (lane == 0) {
        red[0][wid] = s_noobj;
        red[1][wid] = s_obj;
        red[2][wid] = s_coor;
    }
    __syncthreads();
    if (threadIdx.x == 0) {
        atomicAdd(&ws[0], red[0][0] + red[0][1] + red[0][2] + red[0][3]);
        atomicAdd(&ws[1], red[1][0] + red[1][1] + red[1][2] + red[1][3]);
        atomicAdd(&ws[2], red[2][0] + red[2][1] + red[2][2] + red[2][3]);
    }
}

// img_class_loss: one block per batch row, C=1000
__global__ __launch_bounds__(256) void class_loss_kernel(
    const float* __restrict__ scores,   // (64, 1000)
    const int*   __restrict__ label,    // (64,)
    float* __restrict__ ws)
{
    const int b = blockIdx.x;
    const float* row = scores + b * 1000;

    float mx = -INFINITY;
    for (int i = threadIdx.x; i < 1000; i += 256) mx = fmaxf(mx, row[i]);
    #pragma unroll
    for (int off = 32; off > 0; off >>= 1) mx = fmaxf(mx, __shfl_down(mx, off, 64));

    __shared__ float smax[4];
    const int lane = threadIdx.x & 63;
    const int wid  = threadIdx.x >> 6;
    if (lane == 0) smax[wid] = mx;
    __syncthreads();
    mx = fmaxf(fmaxf(smax[0], smax[1]), fmaxf(smax[2], smax[3]));

    float se = 0.0f;
    for (int i = threadIdx.x; i < 1000; i += 256) se += __expf(row[i] - mx);
    #pragma unroll
    for (int off = 32; off > 0; off >>= 1) se += __shfl_down(se, off, 64);

    __shared__ float ssum[4];
    if (lane == 0) ssum[wid] = se;
    __syncthreads();
    if (threadIdx.x == 0) {
        se = ssum[0] + ssum[1] + ssum[2] + ssum[3];
        const float logp = row[label[b]] - mx - __logf(se);
        atomicAdd(&ws[3], -logp * (1.0f / 64.0f));   // mean over B
    }
}

__global__ void finalize_kernel(const float* __restrict__ ws, float* __restrict__ out)
{
    // IMG_CLASS_WEIGHT*class + (0.5*noobj + 1.0*obj + 5.0*coor)/B
    out[0] = ws[3] + (0.5f * ws[0] + 1.0f * ws[1] + 5.0f * ws[2]) * (1.0f / 64.0f);
}

extern "C" void kernel_launch(void* const* d_in, const int* in_sizes, int n_in,
                              void* d_out, int out_size, void* d_ws, size_t ws_size,
                              hipStream_t stream)
{
    const float* objects = (const float*)d_in[0];   // (64,9,128,128)
    const float* scores  = (const float*)d_in[1];   // (64,1000)
    const float* locs    = (const float*)d_in[2];   // (64,9,4,128,128)
    const int*   label   = (const int*)d_in[3];     // (64,)
    const float* gt      = (const float*)d_in[4];   // (64,9,5,128,128)
    float* ws  = (float*)d_ws;
    float* out = (float*)d_out;

    hipMemsetAsync(ws, 0, 4 * sizeof(float), stream);

    main_loss_kernel<<<2304, 256, 0, stream>>>(
        (const float4*)objects, (const float4*)locs, (const float4*)gt, ws);
    class_loss_kernel<<<64, 256, 0, stream>>>(scores, label, ws);
    finalize_kernel<<<1, 1, 0, stream>>>(ws, out);
}